// Round 7
// baseline (118.122 us; speedup 1.0000x reference)
//
#include <hip/hip_runtime.h>
#include <hip/hip_fp16.h>

// ROIAlign3d: input [2,1024,32,16,16] f32, rois [32,5] f32 -> out [32,1024,32,7,7] f32
//
// Round-7 = Round-6 (49.4us) + non-temporal hints on the two streaming paths:
//  - output stores (205MB, write-once): __builtin_nontemporal_store -> nt/sc1
//    evict-first, keeps output from thrashing L2 against staging reads.
//  - input staging loads (64MB, read-once): __builtin_nontemporal_load.
// Everything else identical to R6: fp16 LDS staging [y][x][plane16x2B]
// (CSH=40, RSH=648: both-axis bank-diagonal), 2 x ds_read_b128 per tap,
// packed __hfma2 accumulation, merged 3x3 clamp-shift stencil,
// thread<->(roi,bin) compute/store mapping (proven 202MB, no RMW),
// 28KB LDS -> 5 blocks/CU.

constexpr int kPH = 7, kPW = 7;
constexpr float kSCALE = 0.0625f;
constexpr int kNC = 1024, kNL = 32;
constexpr int kCL = kNC * kNL;            // 32768 planes per batch
constexpr int kNROI = 32;
constexpr int kPPB = 16;                  // (c,l) planes per block
constexpr int kTPB = 256;
constexpr int kCSH = 40;                  // halves per cell (32 planes + 8 pad) = 5 granules
constexpr int kRSH = 16 * kCSH + 8;       // 648 halves per y-row = 81 granules
constexpr int kSPNH = 16 * kRSH;          // 10368 halves = 20736 B
constexpr int kNT = kNROI * kPH;          // 224 table entries per axis
constexpr int kNBIN = kPH * kPW;          // 49

using f32x4 = __attribute__((ext_vector_type(4))) float;

static __device__ __forceinline__ void store_pk4(__half* p, float a, float b,
                                                 float c, float d) {
    union { __half2 h[2]; uint2 u; } pk;
    pk.h[0] = __floats2half2_rn(a, b);
    pk.h[1] = __floats2half2_rn(c, d);
    *reinterpret_cast<uint2*>(p) = pk.u;
}

__global__ __launch_bounds__(kTPB, 5) void roialign3d_kernel(
    const float* __restrict__ input, const float* __restrict__ rois,
    float* __restrict__ out)
{
    __shared__ __align__(16) __half sp[kSPNH];
    __shared__ __align__(16) float4 syt[kNT];   // w0,w1,w2, bitcast(ybase*kRSH)
    __shared__ __align__(16) float4 sxt[kNT];   // w0,w1,w2, bitcast(xbase*kCSH)
    __shared__ int sbofs[kNROI];                // batch offset in halves (0|16)

    const int cl0 = blockIdx.x * kPPB;
    const int tid = threadIdx.x;

    // ---- stage 2 batches x 16 planes -> [y][x][plane16x2B], nt loads ----
    #pragma unroll
    for (int iter = 0; iter < 2; ++iter) {
        const int s   = tid + iter * kTPB;     // 0..511
        const int bb  = s >> 8;                // batch
        const int pg4 = (s >> 6) & 3;          // plane-group 0..3
        const int f   = s & 63;                // float4 position in plane
        const f32x4* src = reinterpret_cast<const f32x4*>(
            input + (size_t)(bb * kCL + cl0 + pg4 * 4) * 256);
        const f32x4 v0 = __builtin_nontemporal_load(src + f);
        const f32x4 v1 = __builtin_nontemporal_load(src + f + 64);
        const f32x4 v2 = __builtin_nontemporal_load(src + f + 128);
        const f32x4 v3 = __builtin_nontemporal_load(src + f + 192);
        const int y  = f >> 2;                 // cell row
        const int x0 = (f & 3) * 4;            // first of 4 cells in the row
        __half* dst = sp + y * kRSH + x0 * kCSH + bb * 16 + pg4 * 4;
        store_pk4(dst + 0 * kCSH, v0.x, v1.x, v2.x, v3.x);
        store_pk4(dst + 1 * kCSH, v0.y, v1.y, v2.y, v3.y);
        store_pk4(dst + 2 * kCSH, v0.z, v1.z, v2.z, v3.z);
        store_pk4(dst + 3 * kCSH, v0.w, v1.w, v2.w, v3.w);
    }

    // ---- merged 3-tap tables: 448 entries ----
    for (int e = tid; e < 2 * kNT; e += kTPB) {
        const int axis = (e >= kNT) ? 1 : 0;   // 0=y, 1=x
        const int idx  = axis ? e - kNT : e;
        const int r = idx / kPH;
        const int g = idx - r * kPH;
        const float lo = rois[r * 5 + (axis ? 1 : 2)] * kSCALE;
        const float hi = rois[r * 5 + (axis ? 3 : 4)] * kSCALE;
        const float sz   = fmaxf(hi - lo, 1.0f);
        const float bin  = sz * (1.0f / 7.0f);
        const float half = bin * 0.5f;
        const float c0r  = lo + (float)g * bin + 0.5f * half;
        float wk0 = 0.f, wk1 = 0.f, wk2 = 0.f;
        int base = 0;
        #pragma unroll
        for (int sidx = 0; sidx < 2; ++sidx) {
            const float coord = c0r + (sidx ? half : 0.f);
            const bool valid = (coord >= -1.0f) && (coord <= 16.0f);
            const float c = fminf(fmaxf(coord, 0.0f), 15.0f);
            const int i0 = (int)floorf(c);
            const int i1 = (i0 + 1 < 16) ? i0 + 1 : 15;
            const float lf = c - (float)i0;
            const float w0 = valid ? (1.0f - lf) * 0.5f : 0.f;  // 0.5: folded 2x2 mean
            const float w1 = valid ? lf * 0.5f : 0.f;
            if (sidx == 0) base = i0;
            const int d0 = i0 - base;          // 0..1 (samples < 1 cell apart)
            const int d1 = i1 - base;          // 0..2
            wk0 += (d0 == 0) ? w0 : 0.f;
            wk1 += (d0 == 1) ? w0 : 0.f;
            wk0 += (d1 == 0) ? w1 : 0.f;
            wk1 += (d1 == 1) ? w1 : 0.f;
            wk2 += (d1 == 2) ? w1 : 0.f;
        }
        // clamp-shift: if base>13 the out-of-range weights are provably zero
        const int sh = (base > 13) ? (base - 13) : 0;          // 0..2
        const float s0 = (sh == 0) ? wk0 : 0.f;
        const float s1 = (sh == 0) ? wk1 : ((sh == 1) ? wk0 : 0.f);
        const float s2 = (sh == 0) ? wk2 : ((sh == 1) ? wk1 : wk0);
        base -= sh;
        float4 tv;
        tv.x = s0; tv.y = s1; tv.z = s2;
        tv.w = __int_as_float(base * (axis ? kCSH : kRSH));
        if (axis) sxt[idx] = tv; else syt[idx] = tv;
    }
    if (tid < kNROI) sbofs[tid] = ((int)rois[tid * 5]) << 4;
    __syncthreads();

    // ---- compute: thread <-> (roi, bin); 16 planes each ----
    for (int it = tid; it < kNROI * kNBIN; it += kTPB) {
        const int r   = it / kNBIN;
        const int bin = it - r * kNBIN;
        const int ph  = bin / kPW;
        const int pw  = bin - ph * kPW;

        const float4 ty = syt[r * kPH + ph];
        const float4 tx = sxt[r * kPW + pw];
        const __half* cp0 = sp + (__float_as_int(ty.w) + __float_as_int(tx.w)
                                  + sbofs[r]);

        const float wy[3] = {ty.x, ty.y, ty.z};
        const float wx[3] = {tx.x, tx.y, tx.z};

        __half2 acc[8];
        const __half2 zz = __floats2half2_rn(0.f, 0.f);
        #pragma unroll
        for (int q = 0; q < 8; ++q) acc[q] = zz;

        #pragma unroll
        for (int i = 0; i < 3; ++i) {
            #pragma unroll
            for (int j = 0; j < 3; ++j) {
                const __half2 wh = __float2half2_rn(wy[i] * wx[j]);
                const __half* cp = cp0 + i * kRSH + j * kCSH;
                union { float4 f; __half2 h[4]; } q0, q1;
                q0.f = *reinterpret_cast<const float4*>(cp);
                q1.f = *reinterpret_cast<const float4*>(cp + 8);
                #pragma unroll
                for (int t = 0; t < 4; ++t) {
                    acc[t]     = __hfma2(q0.h[t], wh, acc[t]);
                    acc[4 + t] = __hfma2(q1.h[t], wh, acc[4 + t]);
                }
            }
        }

        float* dst = out + (size_t)(r * kCL + cl0) * kNBIN + bin;
        #pragma unroll
        for (int q = 0; q < 8; ++q) {
            __builtin_nontemporal_store(__low2float(acc[q]),  dst + (2 * q + 0) * kNBIN);
            __builtin_nontemporal_store(__high2float(acc[q]), dst + (2 * q + 1) * kNBIN);
        }
    }
}

extern "C" void kernel_launch(void* const* d_in, const int* in_sizes, int n_in,
                              void* d_out, int out_size, void* d_ws, size_t ws_size,
                              hipStream_t stream) {
    const float* input = (const float*)d_in[0];
    const float* rois  = (const float*)d_in[1];
    float* out = (float*)d_out;
    roialign3d_kernel<<<dim3(kCL / kPPB), dim3(kTPB), 0, stream>>>(input, rois, out);
}

// Round 8
// 51.704 us; speedup vs baseline: 2.2846x; 2.2846x over previous
//
#include <hip/hip_runtime.h>
#include <hip/hip_fp16.h>

// ROIAlign3d: input [2,1024,32,16,16] f32, rois [32,5] f32 -> out [32,1024,32,7,7] f32
//
// Round-8 = Round-6 (49.4us, proven) + nt LOADS only.
//  - nt stores REVERTED: R7 showed +35% WRITE_SIZE (274MB) and 2.4x slowdown —
//    our 49-dword output rows are not 64B-line-aligned, so evict-first stores
//    defeat L2 partial-line merging -> DRAM RMW. Unaligned streams need L2.
//  - nt loads KEPT: R7 measured FETCH_SIZE 32.8MB (input served from L3,
//    no HBM refetch); loads don't dirty lines -> no RMW risk.
// Rest identical to R6: fp16 LDS staging [y][x][plane16x2B] (CSH=40, RSH=648:
// both-axis bank-diagonal), 2 x ds_read_b128 per tap, packed __hfma2
// accumulation, merged 3x3 clamp-shift stencil, thread<->(roi,bin)
// compute/store mapping (proven 202MB, no RMW), 28KB LDS -> 5 blocks/CU.

constexpr int kPH = 7, kPW = 7;
constexpr float kSCALE = 0.0625f;
constexpr int kNC = 1024, kNL = 32;
constexpr int kCL = kNC * kNL;            // 32768 planes per batch
constexpr int kNROI = 32;
constexpr int kPPB = 16;                  // (c,l) planes per block
constexpr int kTPB = 256;
constexpr int kCSH = 40;                  // halves per cell (32 planes + 8 pad) = 5 granules
constexpr int kRSH = 16 * kCSH + 8;       // 648 halves per y-row = 81 granules
constexpr int kSPNH = 16 * kRSH;          // 10368 halves = 20736 B
constexpr int kNT = kNROI * kPH;          // 224 table entries per axis
constexpr int kNBIN = kPH * kPW;          // 49

using f32x4 = __attribute__((ext_vector_type(4))) float;

static __device__ __forceinline__ void store_pk4(__half* p, float a, float b,
                                                 float c, float d) {
    union { __half2 h[2]; uint2 u; } pk;
    pk.h[0] = __floats2half2_rn(a, b);
    pk.h[1] = __floats2half2_rn(c, d);
    *reinterpret_cast<uint2*>(p) = pk.u;
}

__global__ __launch_bounds__(kTPB, 5) void roialign3d_kernel(
    const float* __restrict__ input, const float* __restrict__ rois,
    float* __restrict__ out)
{
    __shared__ __align__(16) __half sp[kSPNH];
    __shared__ __align__(16) float4 syt[kNT];   // w0,w1,w2, bitcast(ybase*kRSH)
    __shared__ __align__(16) float4 sxt[kNT];   // w0,w1,w2, bitcast(xbase*kCSH)
    __shared__ int sbofs[kNROI];                // batch offset in halves (0|16)

    const int cl0 = blockIdx.x * kPPB;
    const int tid = threadIdx.x;

    // ---- stage 2 batches x 16 planes -> [y][x][plane16x2B], nt loads ----
    #pragma unroll
    for (int iter = 0; iter < 2; ++iter) {
        const int s   = tid + iter * kTPB;     // 0..511
        const int bb  = s >> 8;                // batch
        const int pg4 = (s >> 6) & 3;          // plane-group 0..3
        const int f   = s & 63;                // float4 position in plane
        const f32x4* src = reinterpret_cast<const f32x4*>(
            input + (size_t)(bb * kCL + cl0 + pg4 * 4) * 256);
        const f32x4 v0 = __builtin_nontemporal_load(src + f);
        const f32x4 v1 = __builtin_nontemporal_load(src + f + 64);
        const f32x4 v2 = __builtin_nontemporal_load(src + f + 128);
        const f32x4 v3 = __builtin_nontemporal_load(src + f + 192);
        const int y  = f >> 2;                 // cell row
        const int x0 = (f & 3) * 4;            // first of 4 cells in the row
        __half* dst = sp + y * kRSH + x0 * kCSH + bb * 16 + pg4 * 4;
        store_pk4(dst + 0 * kCSH, v0.x, v1.x, v2.x, v3.x);
        store_pk4(dst + 1 * kCSH, v0.y, v1.y, v2.y, v3.y);
        store_pk4(dst + 2 * kCSH, v0.z, v1.z, v2.z, v3.z);
        store_pk4(dst + 3 * kCSH, v0.w, v1.w, v2.w, v3.w);
    }

    // ---- merged 3-tap tables: 448 entries ----
    for (int e = tid; e < 2 * kNT; e += kTPB) {
        const int axis = (e >= kNT) ? 1 : 0;   // 0=y, 1=x
        const int idx  = axis ? e - kNT : e;
        const int r = idx / kPH;
        const int g = idx - r * kPH;
        const float lo = rois[r * 5 + (axis ? 1 : 2)] * kSCALE;
        const float hi = rois[r * 5 + (axis ? 3 : 4)] * kSCALE;
        const float sz   = fmaxf(hi - lo, 1.0f);
        const float bin  = sz * (1.0f / 7.0f);
        const float half = bin * 0.5f;
        const float c0r  = lo + (float)g * bin + 0.5f * half;
        float wk0 = 0.f, wk1 = 0.f, wk2 = 0.f;
        int base = 0;
        #pragma unroll
        for (int sidx = 0; sidx < 2; ++sidx) {
            const float coord = c0r + (sidx ? half : 0.f);
            const bool valid = (coord >= -1.0f) && (coord <= 16.0f);
            const float c = fminf(fmaxf(coord, 0.0f), 15.0f);
            const int i0 = (int)floorf(c);
            const int i1 = (i0 + 1 < 16) ? i0 + 1 : 15;
            const float lf = c - (float)i0;
            const float w0 = valid ? (1.0f - lf) * 0.5f : 0.f;  // 0.5: folded 2x2 mean
            const float w1 = valid ? lf * 0.5f : 0.f;
            if (sidx == 0) base = i0;
            const int d0 = i0 - base;          // 0..1 (samples < 1 cell apart)
            const int d1 = i1 - base;          // 0..2
            wk0 += (d0 == 0) ? w0 : 0.f;
            wk1 += (d0 == 1) ? w0 : 0.f;
            wk0 += (d1 == 0) ? w1 : 0.f;
            wk1 += (d1 == 1) ? w1 : 0.f;
            wk2 += (d1 == 2) ? w1 : 0.f;
        }
        // clamp-shift: if base>13 the out-of-range weights are provably zero
        const int sh = (base > 13) ? (base - 13) : 0;          // 0..2
        const float s0 = (sh == 0) ? wk0 : 0.f;
        const float s1 = (sh == 0) ? wk1 : ((sh == 1) ? wk0 : 0.f);
        const float s2 = (sh == 0) ? wk2 : ((sh == 1) ? wk1 : wk0);
        base -= sh;
        float4 tv;
        tv.x = s0; tv.y = s1; tv.z = s2;
        tv.w = __int_as_float(base * (axis ? kCSH : kRSH));
        if (axis) sxt[idx] = tv; else syt[idx] = tv;
    }
    if (tid < kNROI) sbofs[tid] = ((int)rois[tid * 5]) << 4;
    __syncthreads();

    // ---- compute: thread <-> (roi, bin); 16 planes each ----
    for (int it = tid; it < kNROI * kNBIN; it += kTPB) {
        const int r   = it / kNBIN;
        const int bin = it - r * kNBIN;
        const int ph  = bin / kPW;
        const int pw  = bin - ph * kPW;

        const float4 ty = syt[r * kPH + ph];
        const float4 tx = sxt[r * kPW + pw];
        const __half* cp0 = sp + (__float_as_int(ty.w) + __float_as_int(tx.w)
                                  + sbofs[r]);

        const float wy[3] = {ty.x, ty.y, ty.z};
        const float wx[3] = {tx.x, tx.y, tx.z};

        __half2 acc[8];
        const __half2 zz = __floats2half2_rn(0.f, 0.f);
        #pragma unroll
        for (int q = 0; q < 8; ++q) acc[q] = zz;

        #pragma unroll
        for (int i = 0; i < 3; ++i) {
            #pragma unroll
            for (int j = 0; j < 3; ++j) {
                const __half2 wh = __float2half2_rn(wy[i] * wx[j]);
                const __half* cp = cp0 + i * kRSH + j * kCSH;
                union { float4 f; __half2 h[4]; } q0, q1;
                q0.f = *reinterpret_cast<const float4*>(cp);
                q1.f = *reinterpret_cast<const float4*>(cp + 8);
                #pragma unroll
                for (int t = 0; t < 4; ++t) {
                    acc[t]     = __hfma2(q0.h[t], wh, acc[t]);
                    acc[4 + t] = __hfma2(q1.h[t], wh, acc[4 + t]);
                }
            }
        }

        float* dst = out + (size_t)(r * kCL + cl0) * kNBIN + bin;
        #pragma unroll
        for (int q = 0; q < 8; ++q) {
            dst[(2 * q + 0) * kNBIN] = __low2float(acc[q]);
            dst[(2 * q + 1) * kNBIN] = __high2float(acc[q]);
        }
    }
}

extern "C" void kernel_launch(void* const* d_in, const int* in_sizes, int n_in,
                              void* d_out, int out_size, void* d_ws, size_t ws_size,
                              hipStream_t stream) {
    const float* input = (const float*)d_in[0];
    const float* rois  = (const float*)d_in[1];
    float* out = (float*)d_out;
    roialign3d_kernel<<<dim3(kCL / kPPB), dim3(kTPB), 0, stream>>>(input, rois, out);
}

// Round 9
// 49.253 us; speedup vs baseline: 2.3983x; 1.0498x over previous
//
#include <hip/hip_runtime.h>
#include <hip/hip_fp16.h>

// ROIAlign3d: input [2,1024,32,16,16] f32, rois [32,5] f32 -> out [32,1024,32,7,7] f32
//
// Round-9 = exact revert to Round-6 (49.4us, measured best).
//  - nt stores (R7): +35% WRITE_SIZE, 2.4x slower — unaligned 49-dword rows
//    need L2 partial-line merging. REVERTED.
//  - nt loads (R8): FETCH halves but dur +4.6% — write-stream-limited, so the
//    fetch saving buys nothing and the low-priority load path costs. REVERTED.
// Final design: fp16 LDS staging [y][x][plane16x2B] (CSH=40 halves, RSH=648:
// both-axis bank-diagonal layout, tap granule group = y+5x+2b+k mod 8),
// 2 x ds_read_b128 per tap covering 16 planes, packed __hfma2 accumulation,
// merged 3x3 clamp-shift stencil (9 taps vs 16), thread<->(roi,bin)
// compute/store mapping (202MB written, no RMW amplification),
// 28KB LDS -> 5 blocks/CU. 268MB logical / 49.4us = 5.4 TB/s combined,
// ~86% of the measured 6.29 TB/s copy ceiling on a 1:3.2 R:W mixed stream.

constexpr int kPH = 7, kPW = 7;
constexpr float kSCALE = 0.0625f;
constexpr int kNC = 1024, kNL = 32;
constexpr int kCL = kNC * kNL;            // 32768 planes per batch
constexpr int kNROI = 32;
constexpr int kPPB = 16;                  // (c,l) planes per block
constexpr int kTPB = 256;
constexpr int kCSH = 40;                  // halves per cell (32 planes + 8 pad) = 5 granules
constexpr int kRSH = 16 * kCSH + 8;       // 648 halves per y-row = 81 granules
constexpr int kSPNH = 16 * kRSH;          // 10368 halves = 20736 B
constexpr int kNT = kNROI * kPH;          // 224 table entries per axis
constexpr int kNBIN = kPH * kPW;          // 49

static __device__ __forceinline__ void store_pk4(__half* p, float a, float b,
                                                 float c, float d) {
    union { __half2 h[2]; uint2 u; } pk;
    pk.h[0] = __floats2half2_rn(a, b);
    pk.h[1] = __floats2half2_rn(c, d);
    *reinterpret_cast<uint2*>(p) = pk.u;
}

__global__ __launch_bounds__(kTPB, 5) void roialign3d_kernel(
    const float* __restrict__ input, const float* __restrict__ rois,
    float* __restrict__ out)
{
    __shared__ __align__(16) __half sp[kSPNH];
    __shared__ __align__(16) float4 syt[kNT];   // w0,w1,w2, bitcast(ybase*kRSH)
    __shared__ __align__(16) float4 sxt[kNT];   // w0,w1,w2, bitcast(xbase*kCSH)
    __shared__ int sbofs[kNROI];                // batch offset in halves (0|16)

    const int cl0 = blockIdx.x * kPPB;
    const int tid = threadIdx.x;

    // ---- stage 2 batches x 16 planes -> [y][x][plane16x2B] ----
    #pragma unroll
    for (int iter = 0; iter < 2; ++iter) {
        const int s   = tid + iter * kTPB;     // 0..511
        const int bb  = s >> 8;                // batch
        const int pg4 = (s >> 6) & 3;          // plane-group 0..3
        const int f   = s & 63;                // float4 position in plane
        const float4* src = reinterpret_cast<const float4*>(
            input + (size_t)(bb * kCL + cl0 + pg4 * 4) * 256);
        const float4 v0 = src[f];
        const float4 v1 = src[f + 64];
        const float4 v2 = src[f + 128];
        const float4 v3 = src[f + 192];
        const int y  = f >> 2;                 // cell row
        const int x0 = (f & 3) * 4;            // first of 4 cells in the row
        __half* dst = sp + y * kRSH + x0 * kCSH + bb * 16 + pg4 * 4;
        store_pk4(dst + 0 * kCSH, v0.x, v1.x, v2.x, v3.x);
        store_pk4(dst + 1 * kCSH, v0.y, v1.y, v2.y, v3.y);
        store_pk4(dst + 2 * kCSH, v0.z, v1.z, v2.z, v3.z);
        store_pk4(dst + 3 * kCSH, v0.w, v1.w, v2.w, v3.w);
    }

    // ---- merged 3-tap tables: 448 entries ----
    for (int e = tid; e < 2 * kNT; e += kTPB) {
        const int axis = (e >= kNT) ? 1 : 0;   // 0=y, 1=x
        const int idx  = axis ? e - kNT : e;
        const int r = idx / kPH;
        const int g = idx - r * kPH;
        const float lo = rois[r * 5 + (axis ? 1 : 2)] * kSCALE;
        const float hi = rois[r * 5 + (axis ? 3 : 4)] * kSCALE;
        const float sz   = fmaxf(hi - lo, 1.0f);
        const float bin  = sz * (1.0f / 7.0f);
        const float half = bin * 0.5f;
        const float c0r  = lo + (float)g * bin + 0.5f * half;
        float wk0 = 0.f, wk1 = 0.f, wk2 = 0.f;
        int base = 0;
        #pragma unroll
        for (int sidx = 0; sidx < 2; ++sidx) {
            const float coord = c0r + (sidx ? half : 0.f);
            const bool valid = (coord >= -1.0f) && (coord <= 16.0f);
            const float c = fminf(fmaxf(coord, 0.0f), 15.0f);
            const int i0 = (int)floorf(c);
            const int i1 = (i0 + 1 < 16) ? i0 + 1 : 15;
            const float lf = c - (float)i0;
            const float w0 = valid ? (1.0f - lf) * 0.5f : 0.f;  // 0.5: folded 2x2 mean
            const float w1 = valid ? lf * 0.5f : 0.f;
            if (sidx == 0) base = i0;
            const int d0 = i0 - base;          // 0..1 (samples < 1 cell apart)
            const int d1 = i1 - base;          // 0..2
            wk0 += (d0 == 0) ? w0 : 0.f;
            wk1 += (d0 == 1) ? w0 : 0.f;
            wk0 += (d1 == 0) ? w1 : 0.f;
            wk1 += (d1 == 1) ? w1 : 0.f;
            wk2 += (d1 == 2) ? w1 : 0.f;
        }
        // clamp-shift: if base>13 the out-of-range weights are provably zero
        const int sh = (base > 13) ? (base - 13) : 0;          // 0..2
        const float s0 = (sh == 0) ? wk0 : 0.f;
        const float s1 = (sh == 0) ? wk1 : ((sh == 1) ? wk0 : 0.f);
        const float s2 = (sh == 0) ? wk2 : ((sh == 1) ? wk1 : wk0);
        base -= sh;
        float4 tv;
        tv.x = s0; tv.y = s1; tv.z = s2;
        tv.w = __int_as_float(base * (axis ? kCSH : kRSH));
        if (axis) sxt[idx] = tv; else syt[idx] = tv;
    }
    if (tid < kNROI) sbofs[tid] = ((int)rois[tid * 5]) << 4;
    __syncthreads();

    // ---- compute: thread <-> (roi, bin); 16 planes each ----
    for (int it = tid; it < kNROI * kNBIN; it += kTPB) {
        const int r   = it / kNBIN;
        const int bin = it - r * kNBIN;
        const int ph  = bin / kPW;
        const int pw  = bin - ph * kPW;

        const float4 ty = syt[r * kPH + ph];
        const float4 tx = sxt[r * kPW + pw];
        const __half* cp0 = sp + (__float_as_int(ty.w) + __float_as_int(tx.w)
                                  + sbofs[r]);

        const float wy[3] = {ty.x, ty.y, ty.z};
        const float wx[3] = {tx.x, tx.y, tx.z};

        __half2 acc[8];
        const __half2 zz = __floats2half2_rn(0.f, 0.f);
        #pragma unroll
        for (int q = 0; q < 8; ++q) acc[q] = zz;

        #pragma unroll
        for (int i = 0; i < 3; ++i) {
            #pragma unroll
            for (int j = 0; j < 3; ++j) {
                const __half2 wh = __float2half2_rn(wy[i] * wx[j]);
                const __half* cp = cp0 + i * kRSH + j * kCSH;
                union { float4 f; __half2 h[4]; } q0, q1;
                q0.f = *reinterpret_cast<const float4*>(cp);
                q1.f = *reinterpret_cast<const float4*>(cp + 8);
                #pragma unroll
                for (int t = 0; t < 4; ++t) {
                    acc[t]     = __hfma2(q0.h[t], wh, acc[t]);
                    acc[4 + t] = __hfma2(q1.h[t], wh, acc[4 + t]);
                }
            }
        }

        float* dst = out + (size_t)(r * kCL + cl0) * kNBIN + bin;
        #pragma unroll
        for (int q = 0; q < 8; ++q) {
            dst[(2 * q + 0) * kNBIN] = __low2float(acc[q]);
            dst[(2 * q + 1) * kNBIN] = __high2float(acc[q]);
        }
    }
}

extern "C" void kernel_launch(void* const* d_in, const int* in_sizes, int n_in,
                              void* d_out, int out_size, void* d_ws, size_t ws_size,
                              hipStream_t stream) {
    const float* input = (const float*)d_in[0];
    const float* rois  = (const float*)d_in[1];
    float* out = (float*)d_out;
    roialign3d_kernel<<<dim3(kCL / kPPB), dim3(kTPB), 0, stream>>>(input, rois, out);
}